// Round 7
// baseline (170.385 us; speedup 1.0000x reference)
//
#include <hip/hip_runtime.h>

#define NF 128
#define NLAT 21
#define NBATCH 2048
#define LEN_T 51
#define NSHIFT 50
#define AUTO_ROWS (NBATCH*LEN_T)   // 104448
#define PRED_ROWS (NBATCH*NSHIFT)  // 102400

typedef short bh8  __attribute__((ext_vector_type(8)));
typedef short bh4  __attribute__((ext_vector_type(4)));
typedef unsigned short us8 __attribute__((ext_vector_type(8)));
typedef float f32x4  __attribute__((ext_vector_type(4)));
typedef float f32x16 __attribute__((ext_vector_type(16)));
typedef unsigned u32x4 __attribute__((ext_vector_type(4)));

#define MFMA32(A,B,C) __builtin_amdgcn_mfma_f32_32x32x16_bf16(A,B,C,0,0,0)
#define SGB(m,n) __builtin_amdgcn_sched_group_barrier((m),(n),0)

// ---------- scalar helpers ----------
__device__ __forceinline__ float bf2f(short s){
  unsigned u = ((unsigned)(unsigned short)s) << 16;
  return __builtin_bit_cast(float, u);
}
__device__ __forceinline__ short f2bf(float v){   // exact RNE (used on inputs)
  unsigned u = __builtin_bit_cast(unsigned, v);
  return (short)((u + 0x7FFFu + ((u>>16)&1u)) >> 16);
}
__device__ __forceinline__ unsigned pk2(float a, float b){  // round-half-up pair pack
  unsigned ua = __builtin_bit_cast(unsigned, a) + 0x8000u;
  unsigned ub = __builtin_bit_cast(unsigned, b) + 0x8000u;
  return (ua >> 16) | (ub & 0xFFFF0000u);
}

// ---------- prep kernels (unchanged layouts) ----------
__global__ void k_mmul(const float* __restrict__ ienc, const float* __restrict__ idec,
                       float* __restrict__ M){
  int idx = blockIdx.x*256 + threadIdx.x;      // 16384
  int i = idx>>7, j = idx&127;
  float s = 0.f;
#pragma unroll
  for(int k=0;k<NLAT;++k) s = fmaf(ienc[i*NLAT+k], idec[k*NF+j], s);
  M[idx] = s;
}

// swizzled bf16 A-operand planes; mats: 0-3 enc_W, 4 enc_Wo, 5-8 dec_W,
// 9 dec_Wo, 10 M, 11 idec^T (K=21 pad). kappa(h,i)=4h+(i&3)+8(i>>2)
// layout (ushort): mat*16384 + (s*4+mt)*512 + lane*8
__global__ void k_prep(const float* __restrict__ encW, const float* __restrict__ encWo,
                       const float* __restrict__ decW, const float* __restrict__ decWo,
                       const float* __restrict__ M,    const float* __restrict__ idec,
                       unsigned short* __restrict__ swz){
  int id  = blockIdx.x*256 + threadIdx.x;  // 12 * 2048
  int mat = id >> 11;
  int rem = id & 2047;
  int f   = rem >> 6, l = rem & 63;
  int s   = f >> 2,  mt = f & 3;
  int hl  = l >> 5,  c  = l & 31;
  const float* src;
  if(mat<4)       src = encW + mat*16384;
  else if(mat==4) src = encWo;
  else if(mat<9)  src = decW + (mat-5)*16384;
  else if(mat==9) src = decWo;
  else if(mat==10)src = M;
  else            src = idec;
  us8 w8;
#pragma unroll
  for(int i=0;i<8;++i){
    int k = s*16 + 4*hl + (i&3) + 8*(i>>2);
    float v;
    if(mat==11) v = (k<NLAT) ? src[k*NF + mt*32 + c] : 0.f;
    else        v = src[k*NF + mt*32 + c];
    w8[i] = (unsigned short)f2bf(v);
  }
  *(us8*)(swz + (size_t)mat*16384 + (size_t)f*512 + (size_t)l*8) = w8;
}

// ---------- async W staging: 8 x global_load_lds(16B) per wave ----------
__device__ __forceinline__ void stage_issue(const unsigned short* g,
                                            unsigned short* lds, int wid, int lane){
  const unsigned short* gp = g + wid*512 + lane*8;
  unsigned short* lp = lds + wid*512;
#pragma unroll
  for(int i=0;i<8;++i){
    __builtin_amdgcn_global_load_lds(
      (const __attribute__((address_space(1))) void*)(gp + i*2048),
      (__attribute__((address_space(3))) void*)(lp + i*2048), 16, 0, 0);
  }
}

// ---------- core: one mt-half (64 feats) over K=128, 2 rowgroups ----------
// acc[g*2+t]; W frag (s, mt=2m+t) at wl + s*2048 + m*1024 + t*512 + lane*8
__device__ __forceinline__ void run_half(const unsigned short* wl, int m,
    const bh8 h[16], f32x16 acc[4], int lane){
  f32x16 z;
#pragma unroll
  for(int r=0;r<16;++r) z[r]=0.f;
  acc[0]=z; acc[1]=z; acc[2]=z; acc[3]=z;
  const unsigned short* base = wl + m*1024 + lane*8;
  bh8 a0 = *(const bh8*)(base);
  bh8 a1 = *(const bh8*)(base + 512);
#pragma unroll
  for(int s=0;s<8;++s){
    bh8 b0, b1;
    if(s<7){
      b0 = *(const bh8*)(base + (s+1)*2048);
      b1 = *(const bh8*)(base + (s+1)*2048 + 512);
      SGB(0x100,2);
    }
    __builtin_amdgcn_s_setprio(1);
    acc[0]=MFMA32(a0,h[s],  acc[0]);
    acc[1]=MFMA32(a1,h[s],  acc[1]);
    acc[2]=MFMA32(a0,h[8+s],acc[2]);
    acc[3]=MFMA32(a1,h[8+s],acc[3]);
    __builtin_amdgcn_s_setprio(0);
    SGB(0x8,4);
    if(s<7){ a0=b0; a1=b1; }
  }
}

// K=32 variant (dec_in = z @ idec): windows 0,1 only
__device__ __forceinline__ void run_half_k2(const unsigned short* wl, int m,
    const bh8 zf[4], f32x16 acc[4], int lane){
  f32x16 z;
#pragma unroll
  for(int r=0;r<16;++r) z[r]=0.f;
  acc[0]=z; acc[1]=z; acc[2]=z; acc[3]=z;
  const unsigned short* base = wl + m*1024 + lane*8;
#pragma unroll
  for(int s=0;s<2;++s){
    bh8 a0 = *(const bh8*)(base + s*2048);
    bh8 a1 = *(const bh8*)(base + s*2048 + 512);
    acc[0]=MFMA32(a0,zf[s],  acc[0]);
    acc[1]=MFMA32(a1,zf[s],  acc[1]);
    acc[2]=MFMA32(a0,zf[2+s],acc[2]);
    acc[3]=MFMA32(a1,zf[2+s],acc[3]);
  }
}

// ---------- epilogues ----------
// hidden: bias+relu -> packed frags; out[g*4 + t*2 + p]
__device__ __forceinline__ void epi_hidden_half(const f32x16 acc[4], const float* bl,
    int m, int hl, bh8 out[8]){
#pragma unroll
  for(int t=0;t<2;++t){
    f32x4 b[4];
#pragma unroll
    for(int q=0;q<4;++q) b[q] = *(const f32x4*)(bl + (2*m+t)*32 + q*8 + hl*4);
#pragma unroll
    for(int g=0;g<2;++g){
      f32x16 a = acc[g*2+t];
#pragma unroll
      for(int q=0;q<4;++q)
#pragma unroll
        for(int j=0;j<4;++j) a[q*4+j] = fmaxf(a[q*4+j] + b[q][j], 0.f);
#pragma unroll
      for(int p=0;p<2;++p){
        u32x4 w;
#pragma unroll
        for(int j=0;j<4;++j) w[j] = pk2(a[p*8+2*j], a[p*8+2*j+1]);
        out[g*4+t*2+p] = __builtin_bit_cast(bh8, w);
      }
    }
  }
}
__device__ __forceinline__ void epi_plain_half(const f32x16 acc[4], bh8 out[8]){
#pragma unroll
  for(int t=0;t<2;++t)
#pragma unroll
    for(int g=0;g<2;++g){
      f32x16 a = acc[g*2+t];
#pragma unroll
      for(int p=0;p<2;++p){
        u32x4 w;
#pragma unroll
        for(int j=0;j<4;++j) w[j] = pk2(a[p*8+2*j], a[p*8+2*j+1]);
        out[g*4+t*2+p] = __builtin_bit_cast(bh8, w);
      }
    }
}

// final: bias + residual(bf16 regs) -> f32 stores
__device__ __forceinline__ void final_half(float* outp, size_t ro0, size_t ro1,
    const f32x16 acc[4], const float* bo, const bh8 res[16], int m, int hl){
#pragma unroll
  for(int t=0;t<2;++t){
    f32x4 b[4];
#pragma unroll
    for(int q=0;q<4;++q) b[q]=*(const f32x4*)(bo + (2*m+t)*32 + q*8 + hl*4);
#pragma unroll
    for(int g=0;g<2;++g){
      f32x16 a = acc[g*2+t];
      bh8 r0 = res[g*8+(2*m+t)*2], r1 = res[g*8+(2*m+t)*2+1];
#pragma unroll
      for(int q=0;q<4;++q)
#pragma unroll
        for(int j=0;j<4;++j){
          int r=q*4+j;
          a[r] += b[q][j] + bf2f((r<8 ? r0 : r1)[r&7]);
        }
      size_t ro = g ? ro1 : ro0;
#pragma unroll
      for(int q=0;q<4;++q){
        f32x4 w; w[0]=a[q*4+0]; w[1]=a[q*4+1]; w[2]=a[q*4+2]; w[3]=a[q*4+3];
        *(f32x4*)(outp + ro + (2*m+t)*32 + q*8 + hl*4) = w;
      }
    }
  }
}

// enc-Wo: bias + residual + pe0 dump (t==0 rows) -> packed frags
__device__ __forceinline__ void peWo_half(const f32x16 acc[4], const float* bo,
    const bh8 res[16], int m, int hl, bh8 out[8], float* __restrict__ pe0,
    int bidx0, int bidx1, bool isz0, bool isz1){
#pragma unroll
  for(int t=0;t<2;++t){
    f32x4 b[4];
#pragma unroll
    for(int q=0;q<4;++q) b[q]=*(const f32x4*)(bo + (2*m+t)*32 + q*8 + hl*4);
#pragma unroll
    for(int g=0;g<2;++g){
      f32x16 a = acc[g*2+t];
      bh8 r0 = res[g*8+(2*m+t)*2], r1 = res[g*8+(2*m+t)*2+1];
#pragma unroll
      for(int q=0;q<4;++q)
#pragma unroll
        for(int j=0;j<4;++j){
          int r=q*4+j;
          a[r] += b[q][j] + bf2f((r<8 ? r0 : r1)[r&7]);
        }
      bool isz = g ? isz1 : isz0;
      int bidx = g ? bidx1 : bidx0;
      if(isz){
#pragma unroll
        for(int q=0;q<4;++q){
          f32x4 w; w[0]=a[q*4+0]; w[1]=a[q*4+1]; w[2]=a[q*4+2]; w[3]=a[q*4+3];
          *(f32x4*)(pe0 + (size_t)bidx*NF + (2*m+t)*32 + q*8 + hl*4) = w;
        }
      }
#pragma unroll
      for(int p=0;p<2;++p){
        u32x4 w;
#pragma unroll
        for(int j=0;j<4;++j) w[j]=pk2(a[p*8+2*j], a[p*8+2*j+1]);
        out[g*4+t*2+p]=__builtin_bit_cast(bh8,w);
      }
    }
  }
}

// ---------- full hidden layer ----------
__device__ __forceinline__ void layer_hidden(const unsigned short* wl, const float* bl,
    bh8 h[16], int lane, int hl){
  f32x16 acc[4]; bh8 t0[8], t1[8];
  run_half(wl,0,h,acc,lane);
  epi_hidden_half(acc,bl,0,hl,t0);
  run_half(wl,1,h,acc,lane);
  epi_hidden_half(acc,bl,1,hl,t1);
#pragma unroll
  for(int g=0;g<2;++g)
#pragma unroll
    for(int k=0;k<4;++k){ h[g*8+k]=t0[g*4+k]; h[g*8+4+k]=t1[g*4+k]; }
}

// ---------- residual stash: wave-private slab of the output it will overwrite ----------
__device__ __forceinline__ void stash16(unsigned short* sp, const bh8 h[16], int lane){
#pragma unroll
  for(int f=0;f<16;++f) *(bh8*)(sp + f*512 + (size_t)lane*8) = h[f];
}
__device__ __forceinline__ void unstash16(const unsigned short* sp, bh8 r[16], int lane){
#pragma unroll
  for(int f=0;f<16;++f) r[f] = *(const bh8*)(sp + f*512 + (size_t)lane*8);
}
// row-scattered variant (k_pred: output rows are permuted)
__device__ __forceinline__ void stash_rows(unsigned short* o3, const bh8 h[16],
    int orow0, int orow1, int hl){
#pragma unroll
  for(int g=0;g<2;++g){
    size_t rb = (size_t)(g?orow1:orow0)*256;
#pragma unroll
    for(int s=0;s<8;++s){
      bh8 v=h[g*8+s];
      bh4 lo=__builtin_shufflevector(v,v,0,1,2,3);
      bh4 hi=__builtin_shufflevector(v,v,4,5,6,7);
      *(bh4*)(o3 + rb + s*16 + 4*hl) = lo;
      *(bh4*)(o3 + rb + s*16 + 8 + 4*hl) = hi;
    }
  }
}
__device__ __forceinline__ void unstash_rows(const unsigned short* o3, bh8 r[16],
    int orow0, int orow1, int hl){
#pragma unroll
  for(int g=0;g<2;++g){
    size_t rb=(size_t)(g?orow1:orow0)*256;
#pragma unroll
    for(int s=0;s<8;++s){
      bh4 lo=*(const bh4*)(o3 + rb + s*16 + 4*hl);
      bh4 hi=*(const bh4*)(o3 + rb + s*16 + 8 + 4*hl);
      r[g*8+s]=__builtin_shufflevector(lo,hi,0,1,2,3,4,5,6,7);
    }
  }
}

// ---------- main fused kernel: 256 rows/block, 64 rows/wave ----------
__global__ __launch_bounds__(256,2)
void k_main3(const float* __restrict__ gin, const unsigned short* __restrict__ swz,
             const float* __restrict__ encB, const float* __restrict__ encBo,
             const float* __restrict__ decB, const float* __restrict__ decBo,
             float* out1, float* out2, float* __restrict__ pe0){
  __shared__ __align__(16) unsigned short wlds[2][16384];  // 64 KB W dbuf
  __shared__ __align__(16) float blds[1280];
  const int tid=threadIdx.x, lane=tid&63, wid=tid>>6;
  const int hl=lane>>5, c31=lane&31;
  const size_t rowbase = (size_t)blockIdx.x*256 + wid*64;
  const int row0 = (int)rowbase + c31, row1 = row0 + 32;
  unsigned short* st2 = (unsigned short*)out2 + rowbase*256;
  unsigned short* st1 = (unsigned short*)out1 + rowbase*256;
  const size_t ro0 = (size_t)row0*NF, ro1 = (size_t)row1*NF;
  const int bidx0 = row0/LEN_T, bidx1 = row1/LEN_T;
  const bool isz0 = (row0 == bidx0*LEN_T), isz1 = (row1 == bidx1*LEN_T);
  bh8 h[16], res[16];

  stage_issue(swz, wlds[0], wid, lane);                     // mat0
  for(int i=tid;i<1280;i+=256)
    blds[i] = (i<512)?encB[i] : (i<1024)?decB[i-512] : (i<1152)?encBo[i-1024] : decBo[i-1152];

  // input frags (RNE) -> h, stash x
#pragma unroll
  for(int g=0;g<2;++g){
    const float* rp = gin + (g?ro1:ro0);
#pragma unroll
    for(int s=0;s<8;++s){
      f32x4 a=*(const f32x4*)(rp + s*16 + 4*hl);
      f32x4 b=*(const f32x4*)(rp + s*16 + 8 + 4*hl);
      us8 o;
#pragma unroll
      for(int i=0;i<4;++i){ o[i]=(unsigned short)f2bf(a[i]); o[i+4]=(unsigned short)f2bf(b[i]); }
      h[g*8+s]=__builtin_bit_cast(bh8,o);
    }
  }
  stash16(st2, h, lane);
  __syncthreads();
  int cur=0;

  // encoder hidden: mats 0..3, stage 1..4
#pragma unroll 1
  for(int l=0;l<4;++l){
    unsigned short* wc = cur?wlds[1]:wlds[0];
    unsigned short* wn = cur?wlds[0]:wlds[1];
    stage_issue(swz + (size_t)(l+1)*16384, wn, wid, lane);
    layer_hidden(wc, blds + l*NF, h, lane, hl);
    __syncthreads(); cur^=1;
  }
  // enc Wo (mat4), stage 5; pe epilogue (res=x)
  {
    unstash16(st2, res, lane);
    unsigned short* wc = cur?wlds[1]:wlds[0];
    unsigned short* wn = cur?wlds[0]:wlds[1];
    stage_issue(swz + (size_t)5*16384, wn, wid, lane);
    f32x16 acc[4]; bh8 t0[8], t1[8];
    run_half(wc,0,h,acc,lane);
    peWo_half(acc, blds+1024, res, 0, hl, t0, pe0, bidx0,bidx1, isz0,isz1);
    run_half(wc,1,h,acc,lane);
    peWo_half(acc, blds+1024, res, 1, hl, t1, pe0, bidx0,bidx1, isz0,isz1);
#pragma unroll
    for(int g=0;g<2;++g)
#pragma unroll
      for(int k=0;k<4;++k){ h[g*8+k]=t0[g*4+k]; h[g*8+4+k]=t1[g*4+k]; }
    stash16(st2, h, lane);                                  // stash pe
    __syncthreads(); cur^=1;
  }
  // pass A hidden: mats 5..8, stage 6..9
#pragma unroll 1
  for(int l=0;l<4;++l){
    unsigned short* wc = cur?wlds[1]:wlds[0];
    unsigned short* wn = cur?wlds[0]:wlds[1];
    stage_issue(swz + (size_t)(6+l)*16384, wn, wid, lane);
    layer_hidden(wc, blds + 512 + l*NF, h, lane, hl);
    __syncthreads(); cur^=1;
  }
  // pass A Wo (mat9), stage 10; final -> out2 (res=pe, stays live for M)
  {
    unstash16(st2, res, lane);
    unsigned short* wc = cur?wlds[1]:wlds[0];
    unsigned short* wn = cur?wlds[0]:wlds[1];
    stage_issue(swz + (size_t)10*16384, wn, wid, lane);
    f32x16 acc[4];
    run_half(wc,0,h,acc,lane);
    final_half(out2, ro0, ro1, acc, blds+1152, res, 0, hl);
    run_half(wc,1,h,acc,lane);
    final_half(out2, ro0, ro1, acc, blds+1152, res, 1, hl);
    __syncthreads(); cur^=1;
  }
  // pd = pe @ M (mat10, B=res), stage 5; stash pd -> out1 slab
  {
    unsigned short* wc = cur?wlds[1]:wlds[0];
    unsigned short* wn = cur?wlds[0]:wlds[1];
    stage_issue(swz + (size_t)5*16384, wn, wid, lane);
    f32x16 acc[4]; bh8 t0[8], t1[8];
    run_half(wc,0,res,acc,lane); epi_plain_half(acc,t0);
    run_half(wc,1,res,acc,lane); epi_plain_half(acc,t1);
#pragma unroll
    for(int g=0;g<2;++g)
#pragma unroll
      for(int k=0;k<4;++k){ h[g*8+k]=t0[g*4+k]; h[g*8+4+k]=t1[g*4+k]; }
    stash16(st1, h, lane);
    __syncthreads(); cur^=1;
  }
  // pass B hidden: mats 5..8, stage 6..9
#pragma unroll 1
  for(int l=0;l<4;++l){
    unsigned short* wc = cur?wlds[1]:wlds[0];
    unsigned short* wn = cur?wlds[0]:wlds[1];
    stage_issue(swz + (size_t)(6+l)*16384, wn, wid, lane);
    layer_hidden(wc, blds + 512 + l*NF, h, lane, hl);
    __syncthreads(); cur^=1;
  }
  // pass B Wo (mat9): final -> out1 (res=pd)
  {
    unstash16(st1, res, lane);
    unsigned short* wc = cur?wlds[1]:wlds[0];
    f32x16 acc[4];
    run_half(wc,0,h,acc,lane);
    final_half(out1, ro0, ro1, acc, blds+1152, res, 0, hl);
    run_half(wc,1,h,acc,lane);
    final_half(out1, ro0, ro1, acc, blds+1152, res, 1, hl);
  }
}

// ---------- rollout (f32 exact) ----------
__global__ void k_roll(const float* __restrict__ pe0, const float* __restrict__ ienc,
                       const float* __restrict__ L, float* __restrict__ zs){
  const int tid=threadIdx.x, lane=tid&63, wid=tid>>6, sub=lane&31, half=lane>>5;
  const int row=blockIdx.x*8 + wid*2 + half;
  const bool act = sub < NLAT;
  float Lc[NLAT];
#pragma unroll
  for(int k=0;k<NLAT;++k) Lc[k] = act ? L[k*NLAT+sub] : 0.f;
  float z=0.f;
  if(act){
    const float* pr = pe0 + (size_t)row*NF;
    float s0=0.f,s1=0.f,s2=0.f,s3=0.f;
#pragma unroll 8
    for(int k=0;k<NF;k+=4){
      s0=fmaf(pr[k+0], ienc[(k+0)*NLAT+sub], s0);
      s1=fmaf(pr[k+1], ienc[(k+1)*NLAT+sub], s1);
      s2=fmaf(pr[k+2], ienc[(k+2)*NLAT+sub], s2);
      s3=fmaf(pr[k+3], ienc[(k+3)*NLAT+sub], s3);
    }
    z=(s0+s1)+(s2+s3);
  }
  const int base = half*32;
#pragma unroll 1
  for(int s=0;s<NSHIFT;++s){
    float zn=0.f;
#pragma unroll
    for(int k=0;k<NLAT;++k) zn=fmaf(__shfl(z, base+k, 64), Lc[k], zn);
    z=zn;
    if(act) zs[((size_t)s*NBATCH + row)*NLAT + sub] = z;
  }
}

// ---------- prediction decode: 256 rows/block, 64 rows/wave ----------
__global__ __launch_bounds__(256,2)
void k_pred3(const float* __restrict__ zs, const unsigned short* __restrict__ swz,
             const float* __restrict__ decB, const float* __restrict__ decBo,
             float* out3){
  __shared__ __align__(16) unsigned short wlds[2][16384];
  __shared__ __align__(16) float blds[640];
  const int tid=threadIdx.x, lane=tid&63, wid=tid>>6;
  const int hl=lane>>5, c31=lane&31;
  const size_t rowbase = (size_t)blockIdx.x*256 + wid*64;
  const int prow0 = (int)rowbase + c31, prow1 = prow0 + 32;
  const int orow0 = (prow0 & 2047)*NSHIFT + (prow0 >> 11);
  const int orow1 = (prow1 & 2047)*NSHIFT + (prow1 >> 11);
  bh8 h[16], res[16];

  stage_issue(swz + (size_t)11*16384, wlds[0], wid, lane);  // idec^T
  for(int i=tid;i<640;i+=256) blds[i] = (i<512) ? decB[i] : decBo[i-512];

  // z frags (guarded K=21, RNE)
  bh8 zf[4];
#pragma unroll
  for(int g=0;g<2;++g){
    const float* zr = zs + (size_t)(g?prow1:prow0)*NLAT;
#pragma unroll
    for(int s=0;s<2;++s){
      us8 o;
#pragma unroll
      for(int i=0;i<8;++i){
        int cc = s*16 + 4*hl + (i&3) + 8*(i>>2);
        o[i] = (cc<NLAT) ? (unsigned short)f2bf(zr[cc]) : (unsigned short)0;
      }
      zf[g*2+s]=__builtin_bit_cast(bh8,o);
    }
  }
  __syncthreads();
  int cur=0;

  // dec_in = z @ idec (mat11), stage 5; stash dec_in (row-scattered)
  {
    unsigned short* wc = wlds[0];
    unsigned short* wn = wlds[1];
    stage_issue(swz + (size_t)5*16384, wn, wid, lane);
    f32x16 acc[4]; bh8 t0[8], t1[8];
    run_half_k2(wc,0,zf,acc,lane); epi_plain_half(acc,t0);
    run_half_k2(wc,1,zf,acc,lane); epi_plain_half(acc,t1);
#pragma unroll
    for(int g=0;g<2;++g)
#pragma unroll
      for(int k=0;k<4;++k){ h[g*8+k]=t0[g*4+k]; h[g*8+4+k]=t1[g*4+k]; }
    stash_rows((unsigned short*)out3, h, orow0, orow1, hl);
    __syncthreads(); cur=1;
  }
  // dec hidden: mats 5..8, stage 6..9
#pragma unroll 1
  for(int l=0;l<4;++l){
    unsigned short* wc = cur?wlds[1]:wlds[0];
    unsigned short* wn = cur?wlds[0]:wlds[1];
    stage_issue(swz + (size_t)(6+l)*16384, wn, wid, lane);
    layer_hidden(wc, blds + l*NF, h, lane, hl);
    __syncthreads(); cur^=1;
  }
  // Wo (mat9): final -> out3 permuted rows
  {
    unstash_rows((const unsigned short*)out3, res, orow0, orow1, hl);
    unsigned short* wc = cur?wlds[1]:wlds[0];
    f32x16 acc[4];
    run_half(wc,0,h,acc,lane);
    final_half(out3, (size_t)orow0*NF, (size_t)orow1*NF, acc, blds+512, res, 0, hl);
    run_half(wc,1,h,acc,lane);
    final_half(out3, (size_t)orow0*NF, (size_t)orow1*NF, acc, blds+512, res, 1, hl);
  }
}

extern "C" void kernel_launch(void* const* d_in, const int* in_sizes, int n_in,
                              void* d_out, int out_size, void* d_ws, size_t ws_size,
                              hipStream_t stream) {
  const float* gin   = (const float*)d_in[0];
  const float* L     = (const float*)d_in[1];
  const float* iencW = (const float*)d_in[2];
  const float* idecW = (const float*)d_in[3];
  const float* encW  = (const float*)d_in[4];
  const float* encB  = (const float*)d_in[5];
  const float* encWo = (const float*)d_in[6];
  const float* encBo = (const float*)d_in[7];
  const float* decW  = (const float*)d_in[8];
  const float* decB  = (const float*)d_in[9];
  const float* decWo = (const float*)d_in[10];
  const float* decBo = (const float*)d_in[11];

  float* out1 = (float*)d_out;                      // autoencoder_output
  float* out2 = out1 + (size_t)AUTO_ROWS*NF;        // outer_auto_output
  float* out3 = out2 + (size_t)AUTO_ROWS*NF;        // predictions

  float* M   = (float*)d_ws;                        // 128*128 f32
  float* pe0 = M + 16384;                           // 2048*128 f32
  float* zs  = pe0 + (size_t)NBATCH*NF;             // 50*2048*21 f32
  unsigned short* swz = (unsigned short*)(zs + (size_t)NSHIFT*NBATCH*NLAT);  // 12*16384 ushort

  hipLaunchKernelGGL(k_mmul, dim3(64),  dim3(256), 0, stream, iencW, idecW, M);
  hipLaunchKernelGGL(k_prep, dim3(96),  dim3(256), 0, stream, encW, encWo, decW, decWo, M, idecW, swz);
  hipLaunchKernelGGL(k_main3, dim3(AUTO_ROWS/256), dim3(256), 0, stream,
                     gin, swz, encB, encBo, decB, decBo, out1, out2, pe0);
  hipLaunchKernelGGL(k_roll, dim3(NBATCH/8), dim3(256), 0, stream, pe0, iencW, L, zs);
  hipLaunchKernelGGL(k_pred3, dim3(PRED_ROWS/256), dim3(256), 0, stream,
                     zs, swz, decB, decBo, out3);
}

// Round 8
// 153.245 us; speedup vs baseline: 1.1118x; 1.1118x over previous
//
#include <hip/hip_runtime.h>

#define NF 128
#define NLAT 21
#define NBATCH 2048
#define LEN_T 51
#define NSHIFT 50
#define AUTO_ROWS (NBATCH*LEN_T)   // 104448
#define PRED_ROWS (NBATCH*NSHIFT)  // 102400

typedef short bh8  __attribute__((ext_vector_type(8)));
typedef unsigned short us8 __attribute__((ext_vector_type(8)));
typedef float f32x4  __attribute__((ext_vector_type(4)));
typedef float f32x16 __attribute__((ext_vector_type(16)));
typedef unsigned u32x4 __attribute__((ext_vector_type(4)));

#define MFMA32(A,B,C) __builtin_amdgcn_mfma_f32_32x32x16_bf16(A,B,C,0,0,0)
#define SGB(m,n) __builtin_amdgcn_sched_group_barrier((m),(n),0)
// masks: VMEM_READ=0x20, MFMA=0x8

// ---------- scalar helpers ----------
__device__ __forceinline__ float bf2f(short s){
  unsigned u = ((unsigned)(unsigned short)s) << 16;
  return __builtin_bit_cast(float, u);
}
__device__ __forceinline__ short f2bf(float v){   // exact RNE
  unsigned u = __builtin_bit_cast(unsigned, v);
  return (short)((u + 0x7FFFu + ((u>>16)&1u)) >> 16);
}
__device__ __forceinline__ unsigned pk2(float a, float b){  // round-half-up pair pack
  unsigned ua = __builtin_bit_cast(unsigned, a) + 0x8000u;
  unsigned ub = __builtin_bit_cast(unsigned, b) + 0x8000u;
  return (ua >> 16) | (ub & 0xFFFF0000u);
}

// ---------- prep kernels (layouts unchanged) ----------
__global__ void k_mmul(const float* __restrict__ ienc, const float* __restrict__ idec,
                       float* __restrict__ M){
  int idx = blockIdx.x*256 + threadIdx.x;      // 16384
  int i = idx>>7, j = idx&127;
  float s = 0.f;
#pragma unroll
  for(int k=0;k<NLAT;++k) s = fmaf(ienc[i*NLAT+k], idec[k*NF+j], s);
  M[idx] = s;
}

// swizzled bf16 A-operand planes; mats: 0-3 enc_W, 4 enc_Wo, 5-8 dec_W,
// 9 dec_Wo, 10 M, 11 idec^T (K=21 pad). kappa(h,i)=4h+(i&3)+8(i>>2)
// layout (ushort): mat*16384 + (s*4+mt)*512 + lane*8   (mt = 2m+t)
__global__ void k_prep(const float* __restrict__ encW, const float* __restrict__ encWo,
                       const float* __restrict__ decW, const float* __restrict__ decWo,
                       const float* __restrict__ M,    const float* __restrict__ idec,
                       unsigned short* __restrict__ swz){
  int id  = blockIdx.x*256 + threadIdx.x;  // 12 * 2048
  int mat = id >> 11;
  int rem = id & 2047;
  int f   = rem >> 6, l = rem & 63;
  int s   = f >> 2,  mt = f & 3;
  int hl  = l >> 5,  c  = l & 31;
  const float* src;
  if(mat<4)       src = encW + mat*16384;
  else if(mat==4) src = encWo;
  else if(mat<9)  src = decW + (mat-5)*16384;
  else if(mat==9) src = decWo;
  else if(mat==10)src = M;
  else            src = idec;
  us8 w8;
#pragma unroll
  for(int i=0;i<8;++i){
    int k = s*16 + 4*hl + (i&3) + 8*(i>>2);
    float v;
    if(mat==11) v = (k<NLAT) ? src[k*NF + mt*32 + c] : 0.f;
    else        v = src[k*NF + mt*32 + c];
    w8[i] = (unsigned short)f2bf(v);
  }
  *(us8*)(swz + (size_t)mat*16384 + (size_t)f*512 + (size_t)l*8) = w8;
}

// ---------- core: one mt-half (64 feats), W direct from global (L1/L2) ----------
// depth-2 prefetch pipeline; acc[g*2+t]
__device__ __forceinline__ bh8 ldg8(const unsigned short* p){ return *(const bh8*)p; }

__device__ __forceinline__ void run_half(const unsigned short* __restrict__ wg, int m,
    const bh8 h[16], f32x16 acc[4], int lane){
  f32x16 z;
#pragma unroll
  for(int r=0;r<16;++r) z[r]=0.f;
  acc[0]=z; acc[1]=z; acc[2]=z; acc[3]=z;
  const unsigned short* base = wg + m*1024 + lane*8;
  bh8 w0a = ldg8(base);
  bh8 w0b = ldg8(base + 512);
  bh8 w1a = ldg8(base + 2048);
  bh8 w1b = ldg8(base + 2048 + 512);
#pragma unroll
  for(int s=0;s<8;++s){
    bh8 na, nb;
    if(s<6){
      na = ldg8(base + (s+2)*2048);
      nb = ldg8(base + (s+2)*2048 + 512);
      SGB(0x20,2);
    }
    __builtin_amdgcn_s_setprio(1);
    acc[0]=MFMA32(w0a,h[s],  acc[0]);
    acc[1]=MFMA32(w0b,h[s],  acc[1]);
    acc[2]=MFMA32(w0a,h[8+s],acc[2]);
    acc[3]=MFMA32(w0b,h[8+s],acc[3]);
    __builtin_amdgcn_s_setprio(0);
    SGB(0x8,4);
    if(s<6){ w0a=w1a; w0b=w1b; w1a=na; w1b=nb; }
    else    { w0a=w1a; w0b=w1b; }
  }
}

// K=32 variant (dec_in = z @ idec): windows 0,1 only
__device__ __forceinline__ void run_half_k2(const unsigned short* __restrict__ wg, int m,
    const bh8 zf[4], f32x16 acc[4], int lane){
  f32x16 z;
#pragma unroll
  for(int r=0;r<16;++r) z[r]=0.f;
  acc[0]=z; acc[1]=z; acc[2]=z; acc[3]=z;
  const unsigned short* base = wg + m*1024 + lane*8;
#pragma unroll
  for(int s=0;s<2;++s){
    bh8 a0 = ldg8(base + s*2048);
    bh8 a1 = ldg8(base + s*2048 + 512);
    acc[0]=MFMA32(a0,zf[s],  acc[0]);
    acc[1]=MFMA32(a1,zf[s],  acc[1]);
    acc[2]=MFMA32(a0,zf[2+s],acc[2]);
    acc[3]=MFMA32(a1,zf[2+s],acc[3]);
  }
}

// ---------- epilogues ----------
__device__ __forceinline__ void epi_hidden_half(const f32x16 acc[4], const float* __restrict__ bl,
    int m, int hl, bh8 out[8]){
#pragma unroll
  for(int t=0;t<2;++t){
    f32x4 b[4];
#pragma unroll
    for(int q=0;q<4;++q) b[q] = *(const f32x4*)(bl + (2*m+t)*32 + q*8 + hl*4);
#pragma unroll
    for(int g=0;g<2;++g){
      f32x16 a = acc[g*2+t];
#pragma unroll
      for(int q=0;q<4;++q)
#pragma unroll
        for(int j=0;j<4;++j) a[q*4+j] = fmaxf(a[q*4+j] + b[q][j], 0.f);
#pragma unroll
      for(int p=0;p<2;++p){
        u32x4 w;
#pragma unroll
        for(int j=0;j<4;++j) w[j] = pk2(a[p*8+2*j], a[p*8+2*j+1]);
        out[g*4+t*2+p] = __builtin_bit_cast(bh8, w);
      }
    }
  }
}
__device__ __forceinline__ void epi_plain_half(const f32x16 acc[4], bh8 out[8]){
#pragma unroll
  for(int t=0;t<2;++t)
#pragma unroll
    for(int g=0;g<2;++g){
      f32x16 a = acc[g*2+t];
#pragma unroll
      for(int p=0;p<2;++p){
        u32x4 w;
#pragma unroll
        for(int j=0;j<4;++j) w[j] = pk2(a[p*8+2*j], a[p*8+2*j+1]);
        out[g*4+t*2+p] = __builtin_bit_cast(bh8, w);
      }
    }
}

// final: bias + residual(r8, per-half) -> f32 stores
__device__ __forceinline__ void final_half(float* outp, size_t ro0, size_t ro1,
    const f32x16 acc[4], const float* __restrict__ bo, const bh8 r8[8], int m, int hl){
#pragma unroll
  for(int t=0;t<2;++t){
    f32x4 b[4];
#pragma unroll
    for(int q=0;q<4;++q) b[q]=*(const f32x4*)(bo + (2*m+t)*32 + q*8 + hl*4);
#pragma unroll
    for(int g=0;g<2;++g){
      f32x16 a = acc[g*2+t];
      bh8 r0 = r8[g*4 + t*2], r1 = r8[g*4 + t*2 + 1];
#pragma unroll
      for(int q=0;q<4;++q)
#pragma unroll
        for(int j=0;j<4;++j){
          int r=q*4+j;
          a[r] += b[q][j] + bf2f((r<8 ? r0 : r1)[r&7]);
        }
      size_t ro = g ? ro1 : ro0;
#pragma unroll
      for(int q=0;q<4;++q){
        f32x4 w; w[0]=a[q*4+0]; w[1]=a[q*4+1]; w[2]=a[q*4+2]; w[3]=a[q*4+3];
        *(f32x4*)(outp + ro + (2*m+t)*32 + q*8 + hl*4) = w;
      }
    }
  }
}

// enc-Wo: bias + residual(r8) + pe0 dump -> packed frags
__device__ __forceinline__ void peWo_half(const f32x16 acc[4], const float* __restrict__ bo,
    const bh8 r8[8], int m, int hl, bh8 out[8], float* __restrict__ pe0,
    int bidx0, int bidx1, bool isz0, bool isz1){
#pragma unroll
  for(int t=0;t<2;++t){
    f32x4 b[4];
#pragma unroll
    for(int q=0;q<4;++q) b[q]=*(const f32x4*)(bo + (2*m+t)*32 + q*8 + hl*4);
#pragma unroll
    for(int g=0;g<2;++g){
      f32x16 a = acc[g*2+t];
      bh8 r0 = r8[g*4 + t*2], r1 = r8[g*4 + t*2 + 1];
#pragma unroll
      for(int q=0;q<4;++q)
#pragma unroll
        for(int j=0;j<4;++j){
          int r=q*4+j;
          a[r] += b[q][j] + bf2f((r<8 ? r0 : r1)[r&7]);
        }
      bool isz = g ? isz1 : isz0;
      int bidx = g ? bidx1 : bidx0;
      if(isz){
#pragma unroll
        for(int q=0;q<4;++q){
          f32x4 w; w[0]=a[q*4+0]; w[1]=a[q*4+1]; w[2]=a[q*4+2]; w[3]=a[q*4+3];
          *(f32x4*)(pe0 + (size_t)bidx*NF + (2*m+t)*32 + q*8 + hl*4) = w;
        }
      }
#pragma unroll
      for(int p=0;p<2;++p){
        u32x4 w;
#pragma unroll
        for(int j=0;j<4;++j) w[j]=pk2(a[p*8+2*j], a[p*8+2*j+1]);
        out[g*4+t*2+p]=__builtin_bit_cast(bh8,w);
      }
    }
  }
}

// ---------- full hidden layer (W + bias from global) ----------
__device__ __forceinline__ void layer_hidden(const unsigned short* __restrict__ wg,
    const float* __restrict__ bl, bh8 h[16], int lane, int hl){
  f32x16 acc[4]; bh8 t0[8], t1[8];
  run_half(wg,0,h,acc,lane);
  epi_hidden_half(acc,bl,0,hl,t0);
  run_half(wg,1,h,acc,lane);
  epi_hidden_half(acc,bl,1,hl,t1);
#pragma unroll
  for(int g=0;g<2;++g)
#pragma unroll
    for(int k=0;k<4;++k){ h[g*8+k]=t0[g*4+k]; h[g*8+4+k]=t1[g*4+k]; }
}

// ---------- residual stash in per-wave LDS (wave-private, no barriers) ----------
__device__ __forceinline__ void stash16(unsigned short* sp, const bh8 h[16], int lane){
#pragma unroll
  for(int f=0;f<16;++f) *(bh8*)(sp + f*512 + lane*8) = h[f];
}
__device__ __forceinline__ void unstash16(const unsigned short* sp, bh8 r[16], int lane){
#pragma unroll
  for(int f=0;f<16;++f) r[f] = *(const bh8*)(sp + f*512 + lane*8);
}
__device__ __forceinline__ void unstash8(const unsigned short* sp, bh8 r8[8], int m, int lane){
#pragma unroll
  for(int g=0;g<2;++g)
#pragma unroll
    for(int k=0;k<4;++k)
      r8[g*4+k] = *(const bh8*)(sp + (g*8 + 4*m + k)*512 + lane*8);
}

// ---------- main fused kernel: 1 wave/block, 64 rows/wave, zero barriers ----------
__global__ __launch_bounds__(64,2)
void k_main4(const float* __restrict__ gin, const unsigned short* __restrict__ swz,
             const float* __restrict__ encB, const float* __restrict__ encBo,
             const float* __restrict__ decB, const float* __restrict__ decBo,
             float* __restrict__ out1, float* __restrict__ out2, float* __restrict__ pe0){
  __shared__ __align__(16) unsigned short sres[8192];   // 16 KB residual slab
  const int lane = threadIdx.x;
  const int hl = lane>>5, c31 = lane&31;
  const size_t rowbase = (size_t)blockIdx.x*64;
  const int row0 = (int)rowbase + c31, row1 = row0 + 32;
  const size_t ro0 = (size_t)row0*NF, ro1 = (size_t)row1*NF;
  const int bidx0 = row0/LEN_T, bidx1 = row1/LEN_T;
  const bool isz0 = (row0 == bidx0*LEN_T), isz1 = (row1 == bidx1*LEN_T);
  bh8 h[16];

  // input frags (RNE) -> h, stash x
#pragma unroll
  for(int g=0;g<2;++g){
    const float* rp = gin + (g?ro1:ro0);
#pragma unroll
    for(int s=0;s<8;++s){
      f32x4 a=*(const f32x4*)(rp + s*16 + 4*hl);
      f32x4 b=*(const f32x4*)(rp + s*16 + 8 + 4*hl);
      us8 o;
#pragma unroll
      for(int i=0;i<4;++i){ o[i]=(unsigned short)f2bf(a[i]); o[i+4]=(unsigned short)f2bf(b[i]); }
      h[g*8+s]=__builtin_bit_cast(bh8,o);
    }
  }
  stash16(sres, h, lane);

  // encoder hidden: mats 0..3
#pragma unroll 1
  for(int l=0;l<4;++l)
    layer_hidden(swz + (size_t)l*16384, encB + l*NF, h, lane, hl);

  // enc Wo (mat4): pe = x + h@Wo + bo; dump t==0 rows; h <- pe; stash pe
  {
    const unsigned short* wg = swz + (size_t)4*16384;
    f32x16 acc[4]; bh8 t0[8], t1[8], r8[8];
    run_half(wg,0,h,acc,lane);
    unstash8(sres, r8, 0, lane);
    peWo_half(acc, encBo, r8, 0, hl, t0, pe0, bidx0,bidx1, isz0,isz1);
    run_half(wg,1,h,acc,lane);
    unstash8(sres, r8, 1, lane);
    peWo_half(acc, encBo, r8, 1, hl, t1, pe0, bidx0,bidx1, isz0,isz1);
#pragma unroll
    for(int g=0;g<2;++g)
#pragma unroll
      for(int k=0;k<4;++k){ h[g*8+k]=t0[g*4+k]; h[g*8+4+k]=t1[g*4+k]; }
    stash16(sres, h, lane);
  }

  // pass A hidden: mats 5..8
#pragma unroll 1
  for(int l=0;l<4;++l)
    layer_hidden(swz + (size_t)(5+l)*16384, decB + l*NF, h, lane, hl);

  // pass A Wo (mat9): out2 = pe + dec(pe)  (pe stays stashed for M)
  {
    const unsigned short* wg = swz + (size_t)9*16384;
    f32x16 acc[4]; bh8 r8[8];
    run_half(wg,0,h,acc,lane);
    unstash8(sres, r8, 0, lane);
    final_half(out2, ro0, ro1, acc, decBo, r8, 0, hl);
    run_half(wg,1,h,acc,lane);
    unstash8(sres, r8, 1, lane);
    final_half(out2, ro0, ro1, acc, decBo, r8, 1, hl);
  }

  // pd = pe @ M (mat10); stash pd
  {
    unstash16(sres, h, lane);                 // h = pe
    const unsigned short* wg = swz + (size_t)10*16384;
    f32x16 acc[4]; bh8 t0[8], t1[8];
    run_half(wg,0,h,acc,lane); epi_plain_half(acc,t0);
    run_half(wg,1,h,acc,lane); epi_plain_half(acc,t1);
#pragma unroll
    for(int g=0;g<2;++g)
#pragma unroll
      for(int k=0;k<4;++k){ h[g*8+k]=t0[g*4+k]; h[g*8+4+k]=t1[g*4+k]; }
    stash16(sres, h, lane);                   // pd
  }

  // pass B hidden: mats 5..8
#pragma unroll 1
  for(int l=0;l<4;++l)
    layer_hidden(swz + (size_t)(5+l)*16384, decB + l*NF, h, lane, hl);

  // pass B Wo (mat9): out1 = pd + dec(pd)
  {
    const unsigned short* wg = swz + (size_t)9*16384;
    f32x16 acc[4]; bh8 r8[8];
    run_half(wg,0,h,acc,lane);
    unstash8(sres, r8, 0, lane);
    final_half(out1, ro0, ro1, acc, decBo, r8, 0, hl);
    run_half(wg,1,h,acc,lane);
    unstash8(sres, r8, 1, lane);
    final_half(out1, ro0, ro1, acc, decBo, r8, 1, hl);
  }
}

// ---------- rollout (f32 exact) ----------
__global__ void k_roll(const float* __restrict__ pe0, const float* __restrict__ ienc,
                       const float* __restrict__ L, float* __restrict__ zs){
  const int tid=threadIdx.x, lane=tid&63, wid=tid>>6, sub=lane&31, half=lane>>5;
  const int row=blockIdx.x*8 + wid*2 + half;
  const bool act = sub < NLAT;
  float Lc[NLAT];
#pragma unroll
  for(int k=0;k<NLAT;++k) Lc[k] = act ? L[k*NLAT+sub] : 0.f;
  float z=0.f;
  if(act){
    const float* pr = pe0 + (size_t)row*NF;
    float s0=0.f,s1=0.f,s2=0.f,s3=0.f;
#pragma unroll 8
    for(int k=0;k<NF;k+=4){
      s0=fmaf(pr[k+0], ienc[(k+0)*NLAT+sub], s0);
      s1=fmaf(pr[k+1], ienc[(k+1)*NLAT+sub], s1);
      s2=fmaf(pr[k+2], ienc[(k+2)*NLAT+sub], s2);
      s3=fmaf(pr[k+3], ienc[(k+3)*NLAT+sub], s3);
    }
    z=(s0+s1)+(s2+s3);
  }
  const int base = half*32;
#pragma unroll 1
  for(int s=0;s<NSHIFT;++s){
    float zn=0.f;
#pragma unroll
    for(int k=0;k<NLAT;++k) zn=fmaf(__shfl(z, base+k, 64), Lc[k], zn);
    z=zn;
    if(act) zs[((size_t)s*NBATCH + row)*NLAT + sub] = z;
  }
}

// ---------- prediction decode: 1 wave/block, 64 rows ----------
__global__ __launch_bounds__(64,2)
void k_pred4(const float* __restrict__ zs, const unsigned short* __restrict__ swz,
             const float* __restrict__ decB, const float* __restrict__ decBo,
             float* __restrict__ out3){
  __shared__ __align__(16) unsigned short sres[8192];
  const int lane = threadIdx.x;
  const int hl = lane>>5, c31 = lane&31;
  const size_t rowbase = (size_t)blockIdx.x*64;
  const int prow0 = (int)rowbase + c31, prow1 = prow0 + 32;
  const int orow0 = (prow0 & 2047)*NSHIFT + (prow0 >> 11);
  const int orow1 = (prow1 & 2047)*NSHIFT + (prow1 >> 11);
  bh8 h[16];

  // z frags (guarded K=21, RNE)
  bh8 zf[4];
#pragma unroll
  for(int g=0;g<2;++g){
    const float* zr = zs + (size_t)(g?prow1:prow0)*NLAT;
#pragma unroll
    for(int s=0;s<2;++s){
      us8 o;
#pragma unroll
      for(int i=0;i<8;++i){
        int cc = s*16 + 4*hl + (i&3) + 8*(i>>2);
        o[i] = (cc<NLAT) ? (unsigned short)f2bf(zr[cc]) : (unsigned short)0;
      }
      zf[g*2+s]=__builtin_bit_cast(bh8,o);
    }
  }

  // dec_in = z @ idec (mat11); stash dec_in
  {
    const unsigned short* wg = swz + (size_t)11*16384;
    f32x16 acc[4]; bh8 t0[8], t1[8];
    run_half_k2(wg,0,zf,acc,lane); epi_plain_half(acc,t0);
    run_half_k2(wg,1,zf,acc,lane); epi_plain_half(acc,t1);
#pragma unroll
    for(int g=0;g<2;++g)
#pragma unroll
      for(int k=0;k<4;++k){ h[g*8+k]=t0[g*4+k]; h[g*8+4+k]=t1[g*4+k]; }
    stash16(sres, h, lane);
  }

  // dec hidden: mats 5..8
#pragma unroll 1
  for(int l=0;l<4;++l)
    layer_hidden(swz + (size_t)(5+l)*16384, decB + l*NF, h, lane, hl);

  // Wo (mat9): out3 (permuted rows) = dec_in + dec(dec_in)
  {
    const unsigned short* wg = swz + (size_t)9*16384;
    f32x16 acc[4]; bh8 r8[8];
    run_half(wg,0,h,acc,lane);
    unstash8(sres, r8, 0, lane);
    final_half(out3, (size_t)orow0*NF, (size_t)orow1*NF, acc, decBo, r8, 0, hl);
    run_half(wg,1,h,acc,lane);
    unstash8(sres, r8, 1, lane);
    final_half(out3, (size_t)orow0*NF, (size_t)orow1*NF, acc, decBo, r8, 1, hl);
  }
}

extern "C" void kernel_launch(void* const* d_in, const int* in_sizes, int n_in,
                              void* d_out, int out_size, void* d_ws, size_t ws_size,
                              hipStream_t stream) {
  const float* gin   = (const float*)d_in[0];
  const float* L     = (const float*)d_in[1];
  const float* iencW = (const float*)d_in[2];
  const float* idecW = (const float*)d_in[3];
  const float* encW  = (const float*)d_in[4];
  const float* encB  = (const float*)d_in[5];
  const float* encWo = (const float*)d_in[6];
  const float* encBo = (const float*)d_in[7];
  const float* decW  = (const float*)d_in[8];
  const float* decB  = (const float*)d_in[9];
  const float* decWo = (const float*)d_in[10];
  const float* decBo = (const float*)d_in[11];

  float* out1 = (float*)d_out;                      // autoencoder_output
  float* out2 = out1 + (size_t)AUTO_ROWS*NF;        // outer_auto_output
  float* out3 = out2 + (size_t)AUTO_ROWS*NF;        // predictions

  float* M   = (float*)d_ws;                        // 128*128 f32
  float* pe0 = M + 16384;                           // 2048*128 f32
  float* zs  = pe0 + (size_t)NBATCH*NF;             // 50*2048*21 f32
  unsigned short* swz = (unsigned short*)(zs + (size_t)NSHIFT*NBATCH*NLAT);  // 12*16384 ushort

  hipLaunchKernelGGL(k_mmul, dim3(64),  dim3(256), 0, stream, iencW, idecW, M);
  hipLaunchKernelGGL(k_prep, dim3(96),  dim3(256), 0, stream, encW, encWo, decW, decWo, M, idecW, swz);
  hipLaunchKernelGGL(k_main4, dim3(AUTO_ROWS/64), dim3(64), 0, stream,
                     gin, swz, encB, encBo, decB, decBo, out1, out2, pe0);
  hipLaunchKernelGGL(k_roll, dim3(NBATCH/8), dim3(256), 0, stream, pe0, iencW, L, zs);
  hipLaunchKernelGGL(k_pred4, dim3(PRED_ROWS/64), dim3(64), 0, stream,
                     zs, swz, decB, decBo, out3);
}